// Round 8
// baseline (2605.432 us; speedup 1.0000x reference)
//
#include <hip/hip_runtime.h>
#include <stdint.h>

typedef _Float16 half8 __attribute__((ext_vector_type(8)));
typedef float f32x4 __attribute__((ext_vector_type(4)));

static constexpr int BN_ = 64;    // batch
static constexpr int TT_ = 512;   // time steps
static constexpr int II_ = 256;   // input dim
static constexpr int HH_ = 512;   // hidden dim
static constexpr int GG_ = 2048;  // 4*H
static constexpr int OO_ = 256;   // output dim

// workspace layout (bytes)
static constexpr size_t GX_OFF    = 0;
static constexpr size_t GX_BYTES  = (size_t)TT_ * BN_ * GG_ * 2;   // 128 MiB fp16 [t][b][g']
static constexpr size_t HALL_OFF  = GX_OFF + GX_BYTES;
static constexpr size_t HALL_BYTES= (size_t)BN_ * TT_ * HH_ * 2;   // 32 MiB fp16 [b][t][u]
static constexpr size_t X_OFF     = HALL_OFF + HALL_BYTES;
static constexpr size_t X_BYTES   = (size_t)2 * 4 * 64 * 16 * 8 * 2; // 128 KiB [par][bg][wave][row16][8u]
static constexpr size_t FLAG_OFF  = X_OFF + X_BYTES;
static constexpr size_t FLAG_BYTES= (size_t)4 * 64 * 128;          // per-wave flag, 128B stride
static constexpr size_t WS_NEEDED = FLAG_OFF + FLAG_BYTES;

__device__ __forceinline__ float sigm(float x)  { return 1.0f / (1.0f + __expf(-x)); }
__device__ __forceinline__ float tanha(float x) { return 1.0f - 2.0f / (__expf(2.0f * x) + 1.0f); }

__device__ __forceinline__ half8 cvt8(float4 a, float4 b) {
  half8 r;
  r[0]=(_Float16)a.x; r[1]=(_Float16)a.y; r[2]=(_Float16)a.z; r[3]=(_Float16)a.w;
  r[4]=(_Float16)b.x; r[5]=(_Float16)b.y; r[6]=(_Float16)b.z; r[7]=(_Float16)b.w;
  return r;
}

// Permutation (unit-interleaved so each lane owns ADJACENT units):
// g' = nb*128 + w*32 + s2*16 + r  ->  unit u = nb*32 + w*8 + (r>>2)*2 + s2,
// gate = r&3.  Original row R(g') = gate*512 + u.

// ---------------------------------------------------------------------------
// Kernel 1: gates_x[t][b][g'] = (x @ W_ih.T)[b,t,R(g')] + b_ih[R] + b_hh[R]
// M=32768 (m=b*512+t), N=2048, K=256. 128x128 tile, BK=32, 4 waves.
// ---------------------------------------------------------------------------
__global__ __launch_bounds__(256) void gates_gemm_k(
    const float* __restrict__ x, const float* __restrict__ Wih,
    const float* __restrict__ bih, const float* __restrict__ bhh,
    _Float16* __restrict__ gx)
{
  __shared__ _Float16 As[128][40];
  __shared__ _Float16 Bs[128][40];
  const int bn = blockIdx.x & 15;
  const int bm = blockIdx.x >> 4;
  const int M0 = bm * 128, N0 = bn * 128;
  const int tid = threadIdx.x;
  const int w = tid >> 6, l = tid & 63, lg = l >> 4, ln = l & 15;
  const int wm = w & 1, wn = w >> 1;
  const int sr = tid >> 1, sp = tid & 1;
  const int nglob = N0 + sr;
  const int qg = nglob & 127;
  const int Rrow = (qg & 3) * HH_ +
                   ((nglob >> 7) << 5) + ((qg >> 5) << 3) +
                   (((qg & 15) >> 2) << 1) + ((qg >> 4) & 1);

  f32x4 acc[4][4];
  #pragma unroll
  for (int i = 0; i < 4; i++) {
    #pragma unroll
    for (int j = 0; j < 4; j++) acc[i][j] = (f32x4){0.f, 0.f, 0.f, 0.f};
  }

  for (int K0 = 0; K0 < II_; K0 += 32) {
    __syncthreads();
    {
      const float* s0 = x + (size_t)(M0 + sr) * II_ + K0 + sp * 16;
      float4 f0 = ((const float4*)s0)[0], f1 = ((const float4*)s0)[1];
      float4 f2 = ((const float4*)s0)[2], f3 = ((const float4*)s0)[3];
      *(half8*)&As[sr][sp * 16]     = cvt8(f0, f1);
      *(half8*)&As[sr][sp * 16 + 8] = cvt8(f2, f3);
      const float* s1 = Wih + (size_t)Rrow * II_ + K0 + sp * 16;
      float4 g0 = ((const float4*)s1)[0], g1 = ((const float4*)s1)[1];
      float4 g2 = ((const float4*)s1)[2], g3 = ((const float4*)s1)[3];
      *(half8*)&Bs[sr][sp * 16]     = cvt8(g0, g1);
      *(half8*)&Bs[sr][sp * 16 + 8] = cvt8(g2, g3);
    }
    __syncthreads();
    half8 af[4], bf[4];
    #pragma unroll
    for (int i = 0; i < 4; i++) af[i] = *(const half8*)&As[wm * 64 + i * 16 + ln][lg * 8];
    #pragma unroll
    for (int j = 0; j < 4; j++) bf[j] = *(const half8*)&Bs[wn * 64 + j * 16 + ln][lg * 8];
    #pragma unroll
    for (int i = 0; i < 4; i++) {
      #pragma unroll
      for (int j = 0; j < 4; j++)
        acc[i][j] = __builtin_amdgcn_mfma_f32_16x16x32_f16(af[i], bf[j], acc[i][j], 0, 0, 0);
    }
  }

  #pragma unroll
  for (int j = 0; j < 4; j++) {
    const int ncol = N0 + wn * 64 + j * 16 + ln;
    const int q = ncol & 127;
    const int u = ((ncol >> 7) << 5) + ((q >> 5) << 3) + (((q & 15) >> 2) << 1) + ((q >> 4) & 1);
    const int R = (q & 3) * HH_ + u;
    const float bias = bih[R] + bhh[R];
    #pragma unroll
    for (int i = 0; i < 4; i++) {
      #pragma unroll
      for (int rr = 0; rr < 4; rr++) {
        const int m = M0 + wm * 64 + i * 16 + lg * 4 + rr;
        const int bb = m >> 9, tt = m & 511;
        gx[(size_t)tt * (BN_ * GG_) + (size_t)bb * GG_ + ncol] =
            (_Float16)(acc[i][j][rr] + bias);
      }
    }
  }
}

// ---------------------------------------------------------------------------
// Kernel 2: persistent LSTM recurrence — wave-granular dataflow, no barriers.
// 64 blocks = 4 batch-groups (mg) x 16 unit-slices (nb); 4 waves each.
// X[par][mg][wave64][row16][8units]: producer wave = ONE coalesced 256B
// dword store (hot full lines). Per-wave flag at 128B stride; consumer lane l
// polls producer wave l's flag (bijective, __all). Flag >= s-1 implies that
// wave's vmcnt(0) drained, which covers its step s-2 bulk READS -> parity
// overwrite safe with no barriers. hall store deferred past the flag so the
// drain covers only the hot X line.
// ---------------------------------------------------------------------------
__global__ __launch_bounds__(256, 1) void lstm_rec_k(
    const float* __restrict__ Whh, const _Float16* __restrict__ gx,
    _Float16* __restrict__ hall, uint32_t* __restrict__ xb,
    int* __restrict__ flags)
{
  const int bid = blockIdx.x;
  const int mg = bid >> 4, nb = bid & 15;
  const int tid = threadIdx.x;
  const int w = tid >> 6, l = tid & 63, lg = l >> 4, ln = l & 15;
  const int batch = mg * 16 + ln;

  // Preload W_hh fragments, rows per interleaved permutation.
  // A-frag row ln of fragment s2: u = nb*32+8w+2*(ln>>2)+s2, gate=ln&3.
  half8 a0[16], a1[16];
  #pragma unroll
  for (int s2 = 0; s2 < 2; s2++) {
    const int u_ = nb * 32 + 8 * w + 2 * (ln >> 2) + s2;
    const int Rr = (ln & 3) * HH_ + u_;
    const float* wp = Whh + (size_t)Rr * HH_;
    #pragma unroll
    for (int ks = 0; ks < 16; ks++) {
      const float* p = wp + ks * 32 + lg * 8;
      float4 f0 = ((const float4*)p)[0];
      float4 f1 = ((const float4*)p)[1];
      if (s2 == 0) a0[ks] = cvt8(f0, f1); else a1[ks] = cvt8(f0, f1);
    }
  }

  const int u0 = nb * 32 + 8 * w + 2 * lg;   // even unit of acc0's lane
  const int g0 = nb * 128 + 32 * w + 4 * lg; // first gate-row (i) of u0
  const int wid = nb * 4 + w;                // wave id within batch-group

  float c0 = 0.f, c1 = 0.f;
  int* myflag = flags + (mg * 64 + wid) * 32;  // this wave's flag line
  int* watch  = flags + (mg * 64 + l) * 32;    // lane l watches wave l

  for (int s = 1; s <= TT_; ++s) {
    const int t = s - 1;
    // gx prefetch (cached; in flight while we poll)
    const _Float16* gxp = gx + (size_t)t * (BN_ * GG_) + (size_t)batch * GG_ + g0;
    uint2 ga = *(const uint2*)gxp;          // gates i,f,g,o of u0
    uint2 gb = *(const uint2*)(gxp + 16);   // gates i,f,g,o of u1

    // poll all 64 producer-wave flags of our batch-group (1 per lane)
    {
      int v; int guard = 0;
      do {
        v = __hip_atomic_load(watch, __ATOMIC_RELAXED, __HIP_MEMORY_SCOPE_SYSTEM);
        if (++guard > (1 << 20)) break;  // deadlock safety valve
      } while (!__all(v >= t));
    }
    __builtin_amdgcn_sched_barrier(0);

    // bulk: for slice ks, lane (lg,ln) reads tile ks*4+lg, row ln (16B = 2xb64)
    const unsigned long long* hin = (const unsigned long long*)xb +
        ((size_t)((t & 1) * 4 + mg) * 64) * 32 + (size_t)ln * 2;
    unsigned long long hw[32];
    #pragma unroll
    for (int ks = 0; ks < 16; ks++) {
      const size_t e = (size_t)(ks * 4 + lg) * 32;
      hw[2 * ks]     = __hip_atomic_load(hin + e,     __ATOMIC_RELAXED, __HIP_MEMORY_SCOPE_SYSTEM);
      hw[2 * ks + 1] = __hip_atomic_load(hin + e + 1, __ATOMIC_RELAXED, __HIP_MEMORY_SCOPE_SYSTEM);
    }

    f32x4 acc0 = {0.f, 0.f, 0.f, 0.f}, acc1 = {0.f, 0.f, 0.f, 0.f};
    #pragma unroll
    for (int ks = 0; ks < 16; ks++) {
      union { unsigned long long q[2]; half8 h; } uq;
      uq.q[0] = hw[2 * ks]; uq.q[1] = hw[2 * ks + 1];
      acc0 = __builtin_amdgcn_mfma_f32_16x16x32_f16(a0[ks], uq.h, acc0, 0, 0, 0);
      acc1 = __builtin_amdgcn_mfma_f32_16x16x32_f16(a1[ks], uq.h, acc1, 0, 0, 0);
    }

    // lane-local cell update: acc regs = i,f,g,o recurrent preacts
    union { uint2 u; _Float16 h[4]; } ua, ub;
    ua.u = ga; ub.u = gb;
    float iv = sigm(acc0[0] + (float)ua.h[0]);
    float fv = sigm(acc0[1] + (float)ua.h[1]);
    float gv = tanha(acc0[2] + (float)ua.h[2]);
    float ov = sigm(acc0[3] + (float)ua.h[3]);
    c0 = fv * c0 + iv * gv;
    const float h0 = ov * tanha(c0);

    iv = sigm(acc1[0] + (float)ub.h[0]);
    fv = sigm(acc1[1] + (float)ub.h[1]);
    gv = tanha(acc1[2] + (float)ub.h[2]);
    ov = sigm(acc1[3] + (float)ub.h[3]);
    c1 = fv * c1 + iv * gv;
    const float h1 = ov * tanha(c1);

    // pack h(u0), h(u0+1) into one dword
    union { _Float16 f; uint16_t u; } cv0, cv1;
    cv0.f = (_Float16)h0; cv1.f = (_Float16)h1;
    const uint32_t packed = ((uint32_t)cv1.u << 16) | (uint32_t)cv0.u;

    // X store: one fully-coalesced dword per lane (wave = 256B, hot lines)
    uint32_t* xp = xb + ((size_t)((s & 1) * 4 + mg) * 64 + wid) * 64 + ln * 4 + lg;
    __hip_atomic_store(xp, packed, __ATOMIC_RELAXED, __HIP_MEMORY_SCOPE_SYSTEM);

    asm volatile("s_waitcnt vmcnt(0)" ::: "memory");  // X store + this step's reads done
    if (l == 0)
      __hip_atomic_store((uint32_t*)myflag, (uint32_t)s,
                         __ATOMIC_RELAXED, __HIP_MEMORY_SCOPE_SYSTEM);

    // hall store AFTER the flag: its cold-line ack rides the next step's slack
    *(uint32_t*)(hall + (size_t)batch * (TT_ * HH_) + (size_t)t * HH_ + u0) = packed;
  }
}

// ---------------------------------------------------------------------------
// Kernel 3: out[b][t][o] = h_all[b][t][:] @ fc_W.T + fc_b   (fp32 out)
// M=32768, N=256, K=512.
// ---------------------------------------------------------------------------
__global__ __launch_bounds__(256) void fc_gemm_k(
    const _Float16* __restrict__ hall, const float* __restrict__ fcW,
    const float* __restrict__ fcb, float* __restrict__ out)
{
  __shared__ _Float16 As[128][40];
  __shared__ _Float16 Bs[128][40];
  const int bn = blockIdx.x & 1;
  const int bm = blockIdx.x >> 1;
  const int M0 = bm * 128, N0 = bn * 128;
  const int tid = threadIdx.x;
  const int w = tid >> 6, l = tid & 63, lg = l >> 4, ln = l & 15;
  const int wm = w & 1, wn = w >> 1;
  const int sr = tid >> 1, sp = tid & 1;

  f32x4 acc[4][4];
  #pragma unroll
  for (int i = 0; i < 4; i++) {
    #pragma unroll
    for (int j = 0; j < 4; j++) acc[i][j] = (f32x4){0.f, 0.f, 0.f, 0.f};
  }

  for (int K0 = 0; K0 < HH_; K0 += 32) {
    __syncthreads();
    {
      const _Float16* s0 = hall + (size_t)(M0 + sr) * HH_ + K0 + sp * 16;
      *(uint4*)&As[sr][sp * 16]     = ((const uint4*)s0)[0];
      *(uint4*)&As[sr][sp * 16 + 8] = ((const uint4*)s0)[1];
      const float* s1 = fcW + (size_t)(N0 + sr) * HH_ + K0 + sp * 16;
      float4 g0 = ((const float4*)s1)[0], g1 = ((const float4*)s1)[1];
      float4 g2 = ((const float4*)s1)[2], g3 = ((const float4*)s1)[3];
      *(half8*)&Bs[sr][sp * 16]     = cvt8(g0, g1);
      *(half8*)&Bs[sr][sp * 16 + 8] = cvt8(g2, g3);
    }
    __syncthreads();
    half8 af[4], bf[4];
    #pragma unroll
    for (int i = 0; i < 4; i++) af[i] = *(const half8*)&As[wm * 64 + i * 16 + ln][lg * 8];
    #pragma unroll
    for (int j = 0; j < 4; j++) bf[j] = *(const half8*)&Bs[wn * 64 + j * 16 + ln][lg * 8];
    #pragma unroll
    for (int i = 0; i < 4; i++) {
      #pragma unroll
      for (int j = 0; j < 4; j++)
        acc[i][j] = __builtin_amdgcn_mfma_f32_16x16x32_f16(af[i], bf[j], acc[i][j], 0, 0, 0);
    }
  }

  #pragma unroll
  for (int j = 0; j < 4; j++) {
    const int ncol = N0 + wn * 64 + j * 16 + ln;
    const float bias = fcb[ncol];
    #pragma unroll
    for (int i = 0; i < 4; i++) {
      #pragma unroll
      for (int rr = 0; rr < 4; rr++) {
        const int m = M0 + wm * 64 + i * 16 + lg * 4 + rr;
        out[(size_t)m * OO_ + ncol] = acc[i][j][rr] + bias;
      }
    }
  }
}

extern "C" void kernel_launch(void* const* d_in, const int* in_sizes, int n_in,
                              void* d_out, int out_size, void* d_ws, size_t ws_size,
                              hipStream_t stream) {
  (void)in_sizes; (void)n_in; (void)out_size;
  if (ws_size < WS_NEEDED) return;  // diagnostic: output stays zero -> absmax ~0.39

  const float* x   = (const float*)d_in[0];
  const float* Wih = (const float*)d_in[1];
  const float* Whh = (const float*)d_in[2];
  const float* bih = (const float*)d_in[3];
  const float* bhh = (const float*)d_in[4];
  const float* fcW = (const float*)d_in[5];
  const float* fcb = (const float*)d_in[6];
  float* out = (float*)d_out;

  char* ws = (char*)d_ws;
  _Float16* gx   = (_Float16*)(ws + GX_OFF);
  _Float16* hall = (_Float16*)(ws + HALL_OFF);
  uint32_t* xb   = (uint32_t*)(ws + X_OFF);
  int* flags     = (int*)(ws + FLAG_OFF);

  // reset X (h0 = 0) and flags every call (graph replays reuse ws)
  (void)hipMemsetAsync(ws + X_OFF, 0, X_BYTES + FLAG_BYTES, stream);

  gates_gemm_k<<<dim3(4096), dim3(256), 0, stream>>>(x, Wih, bih, bhh, gx);
  lstm_rec_k<<<dim3(64), dim3(256), 0, stream>>>(Whh, gx, hall, xb, flags);
  fc_gemm_k<<<dim3(512), dim3(256), 0, stream>>>(hall, fcW, fcb, out);
}

// Round 9
// 2216.764 us; speedup vs baseline: 1.1753x; 1.1753x over previous
//
#include <hip/hip_runtime.h>
#include <stdint.h>

typedef _Float16 half8 __attribute__((ext_vector_type(8)));
typedef float f32x4 __attribute__((ext_vector_type(4)));

static constexpr int BN_ = 64;    // batch
static constexpr int TT_ = 512;   // time steps
static constexpr int II_ = 256;   // input dim
static constexpr int HH_ = 512;   // hidden dim
static constexpr int GG_ = 2048;  // 4*H
static constexpr int OO_ = 256;   // output dim

// workspace layout (bytes)
static constexpr size_t GX_OFF    = 0;
static constexpr size_t GX_BYTES  = (size_t)TT_ * BN_ * GG_ * 2;   // 128 MiB fp16 [t][b][g']
static constexpr size_t HALL_OFF  = GX_OFF + GX_BYTES;
static constexpr size_t HALL_BYTES= (size_t)BN_ * TT_ * HH_ * 2;   // 32 MiB fp16 [b][t][u]
static constexpr size_t X_OFF     = HALL_OFF + HALL_BYTES;
static constexpr size_t X_BYTES   = (size_t)2 * 4 * 64 * 16 * 8 * 2; // 128 KiB [par][bg][wave][row16][8u]
static constexpr size_t FLAG_OFF  = X_OFF + X_BYTES;
static constexpr size_t FLAG_BYTES= (size_t)4 * 64 * 32;           // per-WAVE flag, 32B stride (16 lines/bg)
static constexpr size_t WS_NEEDED = FLAG_OFF + FLAG_BYTES;

__device__ __forceinline__ float sigm(float x)  { return 1.0f / (1.0f + __expf(-x)); }
__device__ __forceinline__ float tanha(float x) { return 1.0f - 2.0f / (__expf(2.0f * x) + 1.0f); }

__device__ __forceinline__ half8 cvt8(float4 a, float4 b) {
  half8 r;
  r[0]=(_Float16)a.x; r[1]=(_Float16)a.y; r[2]=(_Float16)a.z; r[3]=(_Float16)a.w;
  r[4]=(_Float16)b.x; r[5]=(_Float16)b.y; r[6]=(_Float16)b.z; r[7]=(_Float16)b.w;
  return r;
}

// Permutation (unit-interleaved so each lane owns ADJACENT units):
// g' = nb*128 + w*32 + s2*16 + r  ->  unit u = nb*32 + w*8 + (r>>2)*2 + s2,
// gate = r&3.  Original row R(g') = gate*512 + u.

// ---------------------------------------------------------------------------
// Kernel 1: gates_x[t][b][g'] = (x @ W_ih.T)[b,t,R(g')] + b_ih[R] + b_hh[R]
// M=32768 (m=b*512+t), N=2048, K=256. 128x128 tile, BK=32, 4 waves.
// ---------------------------------------------------------------------------
__global__ __launch_bounds__(256) void gates_gemm_k(
    const float* __restrict__ x, const float* __restrict__ Wih,
    const float* __restrict__ bih, const float* __restrict__ bhh,
    _Float16* __restrict__ gx)
{
  __shared__ _Float16 As[128][40];
  __shared__ _Float16 Bs[128][40];
  const int bn = blockIdx.x & 15;
  const int bm = blockIdx.x >> 4;
  const int M0 = bm * 128, N0 = bn * 128;
  const int tid = threadIdx.x;
  const int w = tid >> 6, l = tid & 63, lg = l >> 4, ln = l & 15;
  const int wm = w & 1, wn = w >> 1;
  const int sr = tid >> 1, sp = tid & 1;
  const int nglob = N0 + sr;
  const int qg = nglob & 127;
  const int Rrow = (qg & 3) * HH_ +
                   ((nglob >> 7) << 5) + ((qg >> 5) << 3) +
                   (((qg & 15) >> 2) << 1) + ((qg >> 4) & 1);

  f32x4 acc[4][4];
  #pragma unroll
  for (int i = 0; i < 4; i++) {
    #pragma unroll
    for (int j = 0; j < 4; j++) acc[i][j] = (f32x4){0.f, 0.f, 0.f, 0.f};
  }

  for (int K0 = 0; K0 < II_; K0 += 32) {
    __syncthreads();
    {
      const float* s0 = x + (size_t)(M0 + sr) * II_ + K0 + sp * 16;
      float4 f0 = ((const float4*)s0)[0], f1 = ((const float4*)s0)[1];
      float4 f2 = ((const float4*)s0)[2], f3 = ((const float4*)s0)[3];
      *(half8*)&As[sr][sp * 16]     = cvt8(f0, f1);
      *(half8*)&As[sr][sp * 16 + 8] = cvt8(f2, f3);
      const float* s1 = Wih + (size_t)Rrow * II_ + K0 + sp * 16;
      float4 g0 = ((const float4*)s1)[0], g1 = ((const float4*)s1)[1];
      float4 g2 = ((const float4*)s1)[2], g3 = ((const float4*)s1)[3];
      *(half8*)&Bs[sr][sp * 16]     = cvt8(g0, g1);
      *(half8*)&Bs[sr][sp * 16 + 8] = cvt8(g2, g3);
    }
    __syncthreads();
    half8 af[4], bf[4];
    #pragma unroll
    for (int i = 0; i < 4; i++) af[i] = *(const half8*)&As[wm * 64 + i * 16 + ln][lg * 8];
    #pragma unroll
    for (int j = 0; j < 4; j++) bf[j] = *(const half8*)&Bs[wn * 64 + j * 16 + ln][lg * 8];
    #pragma unroll
    for (int i = 0; i < 4; i++) {
      #pragma unroll
      for (int j = 0; j < 4; j++)
        acc[i][j] = __builtin_amdgcn_mfma_f32_16x16x32_f16(af[i], bf[j], acc[i][j], 0, 0, 0);
    }
  }

  #pragma unroll
  for (int j = 0; j < 4; j++) {
    const int ncol = N0 + wn * 64 + j * 16 + ln;
    const int q = ncol & 127;
    const int u = ((ncol >> 7) << 5) + ((q >> 5) << 3) + (((q & 15) >> 2) << 1) + ((q >> 4) & 1);
    const int R = (q & 3) * HH_ + u;
    const float bias = bih[R] + bhh[R];
    #pragma unroll
    for (int i = 0; i < 4; i++) {
      #pragma unroll
      for (int rr = 0; rr < 4; rr++) {
        const int m = M0 + wm * 64 + i * 16 + lg * 4 + rr;
        const int bb = m >> 9, tt = m & 511;
        gx[(size_t)tt * (BN_ * GG_) + (size_t)bb * GG_ + ncol] =
            (_Float16)(acc[i][j][rr] + bias);
      }
    }
  }
}

// ---------------------------------------------------------------------------
// Kernel 2: persistent LSTM recurrence — r7 structure, per-wave flag publish.
// 64 blocks = 4 batch-groups (mg) x 16 unit-slices (nb); 4 waves each.
// X[par][mg][wave64][row16][8units]: producer wave = ONE coalesced 256B
// dword store (hot full lines). Flags: one per WAVE at 32B stride (16 hot
// lines per bg, same poll surface as r7's block flags). Each wave stores its
// own flag right after its own vmcnt(0) drain — no producer-side barrier,
// no slowest-wave-of-block coupling. Consumer spinner = wave 0 (64 lanes
// watch the 64 wave flags), one __syncthreads releases the block.
// Safety: flag >= s-1 implies that wave's drain covered its step s-2 bulk
// READS -> parity overwrite safe (wave-granular argument, proven in r8).
// ---------------------------------------------------------------------------
__global__ __launch_bounds__(256, 1) void lstm_rec_k(
    const float* __restrict__ Whh, const _Float16* __restrict__ gx,
    _Float16* __restrict__ hall, uint32_t* __restrict__ xb,
    uint32_t* __restrict__ flags)
{
  const int bid = blockIdx.x;
  const int mg = bid >> 4, nb = bid & 15;
  const int tid = threadIdx.x;
  const int w = tid >> 6, l = tid & 63, lg = l >> 4, ln = l & 15;
  const int batch = mg * 16 + ln;

  // Preload W_hh fragments, rows per interleaved permutation.
  // A-frag row ln of fragment s2: u = nb*32+8w+2*(ln>>2)+s2, gate=ln&3.
  half8 a0[16], a1[16];
  #pragma unroll
  for (int s2 = 0; s2 < 2; s2++) {
    const int u_ = nb * 32 + 8 * w + 2 * (ln >> 2) + s2;
    const int Rr = (ln & 3) * HH_ + u_;
    const float* wp = Whh + (size_t)Rr * HH_;
    #pragma unroll
    for (int ks = 0; ks < 16; ks++) {
      const float* p = wp + ks * 32 + lg * 8;
      float4 f0 = ((const float4*)p)[0];
      float4 f1 = ((const float4*)p)[1];
      if (s2 == 0) a0[ks] = cvt8(f0, f1); else a1[ks] = cvt8(f0, f1);
    }
  }

  const int u0 = nb * 32 + 8 * w + 2 * lg;   // even unit of acc0's lane
  const int g0 = nb * 128 + 32 * w + 4 * lg; // first gate-row (i) of u0
  const int wid = nb * 4 + w;                // wave id within batch-group

  float c0 = 0.f, c1 = 0.f;
  uint32_t* myflag = flags + ((size_t)mg * 64 + wid) * 8;  // 32B stride
  const uint32_t* watch = flags + ((size_t)mg * 64 + l) * 8;  // lane l watches wave l

  for (int s = 1; s <= TT_; ++s) {
    const int t = s - 1;
    // gx prefetch (cached; in flight while we poll / wait at the barrier)
    const _Float16* gxp = gx + (size_t)t * (BN_ * GG_) + (size_t)batch * GG_ + g0;
    uint2 ga = *(const uint2*)gxp;          // gates i,f,g,o of u0
    uint2 gb = *(const uint2*)(gxp + 16);   // gates i,f,g,o of u1

    // spinner wave: 64 lanes watch the 64 producer-wave flags of this bg
    if (w == 0) {
      uint32_t v; int guard = 0;
      do {
        v = __hip_atomic_load(watch, __ATOMIC_RELAXED, __HIP_MEMORY_SCOPE_SYSTEM);
        if (++guard > (1 << 20)) break;  // deadlock safety valve
      } while (!__all((int)v >= t));
    }
    __syncthreads();

    // bulk: for slice ks, lane (lg,ln) reads tile ks*4+lg, row ln (16B = 2xb64)
    const unsigned long long* hin = (const unsigned long long*)xb +
        ((size_t)((t & 1) * 4 + mg) * 64) * 32 + (size_t)ln * 2;
    unsigned long long hw[32];
    #pragma unroll
    for (int ks = 0; ks < 16; ks++) {
      const size_t e = (size_t)(ks * 4 + lg) * 32;
      hw[2 * ks]     = __hip_atomic_load(hin + e,     __ATOMIC_RELAXED, __HIP_MEMORY_SCOPE_SYSTEM);
      hw[2 * ks + 1] = __hip_atomic_load(hin + e + 1, __ATOMIC_RELAXED, __HIP_MEMORY_SCOPE_SYSTEM);
    }

    f32x4 acc0 = {0.f, 0.f, 0.f, 0.f}, acc1 = {0.f, 0.f, 0.f, 0.f};
    #pragma unroll
    for (int ks = 0; ks < 16; ks++) {
      union { unsigned long long q[2]; half8 h; } uq;
      uq.q[0] = hw[2 * ks]; uq.q[1] = hw[2 * ks + 1];
      acc0 = __builtin_amdgcn_mfma_f32_16x16x32_f16(a0[ks], uq.h, acc0, 0, 0, 0);
      acc1 = __builtin_amdgcn_mfma_f32_16x16x32_f16(a1[ks], uq.h, acc1, 0, 0, 0);
    }

    // lane-local cell update: acc regs = i,f,g,o recurrent preacts
    union { uint2 u; _Float16 h[4]; } ua, ub;
    ua.u = ga; ub.u = gb;
    float iv = sigm(acc0[0] + (float)ua.h[0]);
    float fv = sigm(acc0[1] + (float)ua.h[1]);
    float gv = tanha(acc0[2] + (float)ua.h[2]);
    float ov = sigm(acc0[3] + (float)ua.h[3]);
    c0 = fv * c0 + iv * gv;
    const float h0 = ov * tanha(c0);

    iv = sigm(acc1[0] + (float)ub.h[0]);
    fv = sigm(acc1[1] + (float)ub.h[1]);
    gv = tanha(acc1[2] + (float)ub.h[2]);
    ov = sigm(acc1[3] + (float)ub.h[3]);
    c1 = fv * c1 + iv * gv;
    const float h1 = ov * tanha(c1);

    // pack h(u0), h(u0+1) into one dword
    union { _Float16 f; uint16_t u; } cv0, cv1;
    cv0.f = (_Float16)h0; cv1.f = (_Float16)h1;
    const uint32_t packed = ((uint32_t)cv1.u << 16) | (uint32_t)cv0.u;

    // X store: one fully-coalesced dword per lane (wave = 256B, hot lines)
    uint32_t* xp = xb + ((size_t)((s & 1) * 4 + mg) * 64 + wid) * 64 + ln * 4 + lg;
    __hip_atomic_store(xp, packed, __ATOMIC_RELAXED, __HIP_MEMORY_SCOPE_SYSTEM);
    // hall: cached dword store; its ack overlaps the X ack inside one drain
    *(uint32_t*)(hall + (size_t)batch * (TT_ * HH_) + (size_t)t * HH_ + u0) = packed;

    asm volatile("s_waitcnt vmcnt(0)" ::: "memory");  // stores + this step's reads done
    if (l == 0)   // lane 0 of EVERY wave publishes its own flag immediately
      __hip_atomic_store(myflag, (uint32_t)s,
                         __ATOMIC_RELAXED, __HIP_MEMORY_SCOPE_SYSTEM);
  }
}

// ---------------------------------------------------------------------------
// Kernel 3: out[b][t][o] = h_all[b][t][:] @ fc_W.T + fc_b   (fp32 out)
// M=32768, N=256, K=512.
// ---------------------------------------------------------------------------
__global__ __launch_bounds__(256) void fc_gemm_k(
    const _Float16* __restrict__ hall, const float* __restrict__ fcW,
    const float* __restrict__ fcb, float* __restrict__ out)
{
  __shared__ _Float16 As[128][40];
  __shared__ _Float16 Bs[128][40];
  const int bn = blockIdx.x & 1;
  const int bm = blockIdx.x >> 1;
  const int M0 = bm * 128, N0 = bn * 128;
  const int tid = threadIdx.x;
  const int w = tid >> 6, l = tid & 63, lg = l >> 4, ln = l & 15;
  const int wm = w & 1, wn = w >> 1;
  const int sr = tid >> 1, sp = tid & 1;

  f32x4 acc[4][4];
  #pragma unroll
  for (int i = 0; i < 4; i++) {
    #pragma unroll
    for (int j = 0; j < 4; j++) acc[i][j] = (f32x4){0.f, 0.f, 0.f, 0.f};
  }

  for (int K0 = 0; K0 < HH_; K0 += 32) {
    __syncthreads();
    {
      const _Float16* s0 = hall + (size_t)(M0 + sr) * HH_ + K0 + sp * 16;
      *(uint4*)&As[sr][sp * 16]     = ((const uint4*)s0)[0];
      *(uint4*)&As[sr][sp * 16 + 8] = ((const uint4*)s0)[1];
      const float* s1 = fcW + (size_t)(N0 + sr) * HH_ + K0 + sp * 16;
      float4 g0 = ((const float4*)s1)[0], g1 = ((const float4*)s1)[1];
      float4 g2 = ((const float4*)s1)[2], g3 = ((const float4*)s1)[3];
      *(half8*)&Bs[sr][sp * 16]     = cvt8(g0, g1);
      *(half8*)&Bs[sr][sp * 16 + 8] = cvt8(g2, g3);
    }
    __syncthreads();
    half8 af[4], bf[4];
    #pragma unroll
    for (int i = 0; i < 4; i++) af[i] = *(const half8*)&As[wm * 64 + i * 16 + ln][lg * 8];
    #pragma unroll
    for (int j = 0; j < 4; j++) bf[j] = *(const half8*)&Bs[wn * 64 + j * 16 + ln][lg * 8];
    #pragma unroll
    for (int i = 0; i < 4; i++) {
      #pragma unroll
      for (int j = 0; j < 4; j++)
        acc[i][j] = __builtin_amdgcn_mfma_f32_16x16x32_f16(af[i], bf[j], acc[i][j], 0, 0, 0);
    }
  }

  #pragma unroll
  for (int j = 0; j < 4; j++) {
    const int ncol = N0 + wn * 64 + j * 16 + ln;
    const float bias = fcb[ncol];
    #pragma unroll
    for (int i = 0; i < 4; i++) {
      #pragma unroll
      for (int rr = 0; rr < 4; rr++) {
        const int m = M0 + wm * 64 + i * 16 + lg * 4 + rr;
        out[(size_t)m * OO_ + ncol] = acc[i][j][rr] + bias;
      }
    }
  }
}

extern "C" void kernel_launch(void* const* d_in, const int* in_sizes, int n_in,
                              void* d_out, int out_size, void* d_ws, size_t ws_size,
                              hipStream_t stream) {
  (void)in_sizes; (void)n_in; (void)out_size;
  if (ws_size < WS_NEEDED) return;  // diagnostic: output stays zero -> absmax ~0.39

  const float* x   = (const float*)d_in[0];
  const float* Wih = (const float*)d_in[1];
  const float* Whh = (const float*)d_in[2];
  const float* bih = (const float*)d_in[3];
  const float* bhh = (const float*)d_in[4];
  const float* fcW = (const float*)d_in[5];
  const float* fcb = (const float*)d_in[6];
  float* out = (float*)d_out;

  char* ws = (char*)d_ws;
  _Float16* gx    = (_Float16*)(ws + GX_OFF);
  _Float16* hall  = (_Float16*)(ws + HALL_OFF);
  uint32_t* xb    = (uint32_t*)(ws + X_OFF);
  uint32_t* flags = (uint32_t*)(ws + FLAG_OFF);

  // reset X (h0 = 0) and flags every call (graph replays reuse ws)
  (void)hipMemsetAsync(ws + X_OFF, 0, X_BYTES + FLAG_BYTES, stream);

  gates_gemm_k<<<dim3(4096), dim3(256), 0, stream>>>(x, Wih, bih, bhh, gx);
  lstm_rec_k<<<dim3(64), dim3(256), 0, stream>>>(Whh, gx, hall, xb, flags);
  fc_gemm_k<<<dim3(512), dim3(256), 0, stream>>>(hall, fcW, fcb, out);
}

// Round 10
// 2008.579 us; speedup vs baseline: 1.2972x; 1.1036x over previous
//
#include <hip/hip_runtime.h>
#include <stdint.h>

typedef _Float16 half8 __attribute__((ext_vector_type(8)));
typedef float f32x4 __attribute__((ext_vector_type(4)));

static constexpr int BN_ = 64;    // batch
static constexpr int TT_ = 512;   // time steps
static constexpr int II_ = 256;   // input dim
static constexpr int HH_ = 512;   // hidden dim
static constexpr int GG_ = 2048;  // 4*H
static constexpr int OO_ = 256;   // output dim

// workspace layout (bytes)
static constexpr size_t GX_OFF    = 0;
static constexpr size_t GX_BYTES  = (size_t)TT_ * BN_ * GG_ * 2;   // 128 MiB fp16 [t][b][g']
static constexpr size_t HH_OFF    = GX_OFF + GX_BYTES;
// Hh[slot 513][bg 4][wave 64][row16][8u] dwords — coalesced 256B/wave/step.
// Slot s holds h_s (slot 0 = zeros = h_0). Exchange buffer AND FC input.
static constexpr size_t HH_BYTES  = (size_t)(TT_ + 1) * 4 * 64 * 256;  // 32.06 MiB
static constexpr size_t FLAG_OFF  = HH_OFF + HH_BYTES;
static constexpr size_t FLAG_BYTES= (size_t)64 * 128;              // one 128B slot per block
static constexpr size_t WS_NEEDED = FLAG_OFF + FLAG_BYTES;

__device__ __forceinline__ float sigm(float x)  { return 1.0f / (1.0f + __expf(-x)); }
__device__ __forceinline__ float tanha(float x) { return 1.0f - 2.0f / (__expf(2.0f * x) + 1.0f); }

__device__ __forceinline__ half8 cvt8(float4 a, float4 b) {
  half8 r;
  r[0]=(_Float16)a.x; r[1]=(_Float16)a.y; r[2]=(_Float16)a.z; r[3]=(_Float16)a.w;
  r[4]=(_Float16)b.x; r[5]=(_Float16)b.y; r[6]=(_Float16)b.z; r[7]=(_Float16)b.w;
  return r;
}

// Permutation (unit-interleaved so each lane owns ADJACENT units):
// g' = nb*128 + w*32 + s2*16 + r  ->  unit u = nb*32 + w*8 + (r>>2)*2 + s2,
// gate = r&3.  Original row R(g') = gate*512 + u.

// ---------------------------------------------------------------------------
// Kernel 1: gates_x[t][b][g'] = (x @ W_ih.T)[b,t,R(g')] + b_ih[R] + b_hh[R]
// M=32768 (m=b*512+t), N=2048, K=256. 128x128 tile, BK=32, 4 waves.
// ---------------------------------------------------------------------------
__global__ __launch_bounds__(256) void gates_gemm_k(
    const float* __restrict__ x, const float* __restrict__ Wih,
    const float* __restrict__ bih, const float* __restrict__ bhh,
    _Float16* __restrict__ gx)
{
  __shared__ _Float16 As[128][40];
  __shared__ _Float16 Bs[128][40];
  const int bn = blockIdx.x & 15;
  const int bm = blockIdx.x >> 4;
  const int M0 = bm * 128, N0 = bn * 128;
  const int tid = threadIdx.x;
  const int w = tid >> 6, l = tid & 63, lg = l >> 4, ln = l & 15;
  const int wm = w & 1, wn = w >> 1;
  const int sr = tid >> 1, sp = tid & 1;
  const int nglob = N0 + sr;
  const int qg = nglob & 127;
  const int Rrow = (qg & 3) * HH_ +
                   ((nglob >> 7) << 5) + ((qg >> 5) << 3) +
                   (((qg & 15) >> 2) << 1) + ((qg >> 4) & 1);

  f32x4 acc[4][4];
  #pragma unroll
  for (int i = 0; i < 4; i++) {
    #pragma unroll
    for (int j = 0; j < 4; j++) acc[i][j] = (f32x4){0.f, 0.f, 0.f, 0.f};
  }

  for (int K0 = 0; K0 < II_; K0 += 32) {
    __syncthreads();
    {
      const float* s0 = x + (size_t)(M0 + sr) * II_ + K0 + sp * 16;
      float4 f0 = ((const float4*)s0)[0], f1 = ((const float4*)s0)[1];
      float4 f2 = ((const float4*)s0)[2], f3 = ((const float4*)s0)[3];
      *(half8*)&As[sr][sp * 16]     = cvt8(f0, f1);
      *(half8*)&As[sr][sp * 16 + 8] = cvt8(f2, f3);
      const float* s1 = Wih + (size_t)Rrow * II_ + K0 + sp * 16;
      float4 g0 = ((const float4*)s1)[0], g1 = ((const float4*)s1)[1];
      float4 g2 = ((const float4*)s1)[2], g3 = ((const float4*)s1)[3];
      *(half8*)&Bs[sr][sp * 16]     = cvt8(g0, g1);
      *(half8*)&Bs[sr][sp * 16 + 8] = cvt8(g2, g3);
    }
    __syncthreads();
    half8 af[4], bf[4];
    #pragma unroll
    for (int i = 0; i < 4; i++) af[i] = *(const half8*)&As[wm * 64 + i * 16 + ln][lg * 8];
    #pragma unroll
    for (int j = 0; j < 4; j++) bf[j] = *(const half8*)&Bs[wn * 64 + j * 16 + ln][lg * 8];
    #pragma unroll
    for (int i = 0; i < 4; i++) {
      #pragma unroll
      for (int j = 0; j < 4; j++)
        acc[i][j] = __builtin_amdgcn_mfma_f32_16x16x32_f16(af[i], bf[j], acc[i][j], 0, 0, 0);
    }
  }

  #pragma unroll
  for (int j = 0; j < 4; j++) {
    const int ncol = N0 + wn * 64 + j * 16 + ln;
    const int q = ncol & 127;
    const int u = ((ncol >> 7) << 5) + ((q >> 5) << 3) + (((q & 15) >> 2) << 1) + ((q >> 4) & 1);
    const int R = (q & 3) * HH_ + u;
    const float bias = bih[R] + bhh[R];
    #pragma unroll
    for (int i = 0; i < 4; i++) {
      #pragma unroll
      for (int rr = 0; rr < 4; rr++) {
        const int m = M0 + wm * 64 + i * 16 + lg * 4 + rr;
        const int bb = m >> 9, tt = m & 511;
        gx[(size_t)tt * (BN_ * GG_) + (size_t)bb * GG_ + ncol] =
            (_Float16)(acc[i][j][rr] + bias);
      }
    }
  }
}

// ---------------------------------------------------------------------------
// Kernel 2: persistent LSTM recurrence — r7 protocol, unified coalesced
// history buffer. 64 blocks = 4 batch-groups (mg) x 16 unit-slices (nb).
// Hh[slot][mg][wave][row16][8u]: producer wave's step output is ONE coalesced
// 256B dword store (full-line even when cold -> no MALL RMW); this store IS
// the history the FC pass reads — no separate hall store, so the vmcnt(0)
// drain before the flag covers only the one full-line ack.
// Flags/poll/barriers: r7 verbatim (block flag, tid<16 spinners, 2 barriers).
// ---------------------------------------------------------------------------
__global__ __launch_bounds__(256, 1) void lstm_rec_k(
    const float* __restrict__ Whh, const _Float16* __restrict__ gx,
    uint32_t* __restrict__ hh, int* __restrict__ flags)
{
  const int bid = blockIdx.x;
  const int mg = bid >> 4, nb = bid & 15;
  const int tid = threadIdx.x;
  const int w = tid >> 6, l = tid & 63, lg = l >> 4, ln = l & 15;
  const int batch = mg * 16 + ln;

  // Preload W_hh fragments, rows per interleaved permutation.
  // A-frag row ln of fragment s2: u = nb*32+8w+2*(ln>>2)+s2, gate=ln&3.
  half8 a0[16], a1[16];
  #pragma unroll
  for (int s2 = 0; s2 < 2; s2++) {
    const int u_ = nb * 32 + 8 * w + 2 * (ln >> 2) + s2;
    const int Rr = (ln & 3) * HH_ + u_;
    const float* wp = Whh + (size_t)Rr * HH_;
    #pragma unroll
    for (int ks = 0; ks < 16; ks++) {
      const float* p = wp + ks * 32 + lg * 8;
      float4 f0 = ((const float4*)p)[0];
      float4 f1 = ((const float4*)p)[1];
      if (s2 == 0) a0[ks] = cvt8(f0, f1); else a1[ks] = cvt8(f0, f1);
    }
  }

  const int g0 = nb * 128 + 32 * w + 4 * lg; // first gate-row (i) of u0
  const int wid = nb * 4 + w;                // wave id within batch-group

  float c0 = 0.f, c1 = 0.f;
  int* myflag = flags + bid * 32;
  int* watch = flags + (mg * 16 + (tid & 15)) * 32;
  const bool spinner = (tid < 16) && (tid != nb);

  for (int s = 1; s <= TT_; ++s) {
    const int t = s - 1;
    // gx prefetch (cached; in flight while we poll)
    const _Float16* gxp = gx + (size_t)t * (BN_ * GG_) + (size_t)batch * GG_ + g0;
    uint2 ga = *(const uint2*)gxp;          // gates i,f,g,o of u0
    uint2 gb = *(const uint2*)(gxp + 16);   // gates i,f,g,o of u1

    // wait until all partner blocks have published h_{s-1}
    if (spinner) {
      int guard = 0;
      while (__hip_atomic_load(watch, __ATOMIC_RELAXED, __HIP_MEMORY_SCOPE_SYSTEM) < s - 1) {
        if (++guard > (1 << 20)) break;  // deadlock safety valve
      }
    }
    __syncthreads();

    // bulk: slice ks -> tile ks*4+lg, row ln (16B = 2xb64) of slot t
    const unsigned long long* hin = (const unsigned long long*)hh +
        ((size_t)t * 4 + mg) * (64 * 32) + (size_t)ln * 2;
    unsigned long long hw[32];
    #pragma unroll
    for (int ks = 0; ks < 16; ks++) {
      const size_t e = (size_t)(ks * 4 + lg) * 32;
      hw[2 * ks]     = __hip_atomic_load(hin + e,     __ATOMIC_RELAXED, __HIP_MEMORY_SCOPE_SYSTEM);
      hw[2 * ks + 1] = __hip_atomic_load(hin + e + 1, __ATOMIC_RELAXED, __HIP_MEMORY_SCOPE_SYSTEM);
    }

    f32x4 acc0 = {0.f, 0.f, 0.f, 0.f}, acc1 = {0.f, 0.f, 0.f, 0.f};
    #pragma unroll
    for (int ks = 0; ks < 16; ks++) {
      union { unsigned long long q[2]; half8 h; } uq;
      uq.q[0] = hw[2 * ks]; uq.q[1] = hw[2 * ks + 1];
      acc0 = __builtin_amdgcn_mfma_f32_16x16x32_f16(a0[ks], uq.h, acc0, 0, 0, 0);
      acc1 = __builtin_amdgcn_mfma_f32_16x16x32_f16(a1[ks], uq.h, acc1, 0, 0, 0);
    }

    // lane-local cell update: acc regs = i,f,g,o recurrent preacts
    union { uint2 u; _Float16 h[4]; } ua, ub;
    ua.u = ga; ub.u = gb;
    float iv = sigm(acc0[0] + (float)ua.h[0]);
    float fv = sigm(acc0[1] + (float)ua.h[1]);
    float gv = tanha(acc0[2] + (float)ua.h[2]);
    float ov = sigm(acc0[3] + (float)ua.h[3]);
    c0 = fv * c0 + iv * gv;
    const float h0 = ov * tanha(c0);

    iv = sigm(acc1[0] + (float)ub.h[0]);
    fv = sigm(acc1[1] + (float)ub.h[1]);
    gv = tanha(acc1[2] + (float)ub.h[2]);
    ov = sigm(acc1[3] + (float)ub.h[3]);
    c1 = fv * c1 + iv * gv;
    const float h1 = ov * tanha(c1);

    // pack h(u0), h(u0+1) into one dword
    union { _Float16 f; uint16_t u; } cv0, cv1;
    cv0.f = (_Float16)h0; cv1.f = (_Float16)h1;
    const uint32_t packed = ((uint32_t)cv1.u << 16) | (uint32_t)cv0.u;

    // SINGLE store: coalesced dword into slot s (wave = 256B full lines).
    // This is both the exchange data and the FC-pass history.
    uint32_t* xp = hh + ((size_t)s * 4 + mg) * (64 * 64) + (size_t)wid * 64 + ln * 4 + lg;
    __hip_atomic_store(xp, packed, __ATOMIC_RELAXED, __HIP_MEMORY_SCOPE_SYSTEM);

    asm volatile("s_waitcnt vmcnt(0)" ::: "memory");  // one full-line ack
    __syncthreads();                                   // all waves of block done
    if (tid == 0)
      __hip_atomic_store(myflag, s, __ATOMIC_RELAXED, __HIP_MEMORY_SCOPE_SYSTEM);
  }
}

// ---------------------------------------------------------------------------
// Kernel 3: out[b][t][o] = h_{t+1}[b][:] @ fc_W.T + fc_b   (fp32 out)
// A-operand read from Hh's tiled layout: for (b, t, 8-unit group G) the 16B
// chunk lives at dword ((slot*4+mg)*64 + G)*64 + (b&15)*4, slot = t+1.
// M=32768, N=256, K=512.
// ---------------------------------------------------------------------------
__global__ __launch_bounds__(256) void fc_gemm_k(
    const uint32_t* __restrict__ hh, const float* __restrict__ fcW,
    const float* __restrict__ fcb, float* __restrict__ out)
{
  __shared__ _Float16 As[128][40];
  __shared__ _Float16 Bs[128][40];
  const int bn = blockIdx.x & 1;
  const int bm = blockIdx.x >> 1;
  const int M0 = bm * 128, N0 = bn * 128;
  const int tid = threadIdx.x;
  const int w = tid >> 6, l = tid & 63, lg = l >> 4, ln = l & 15;
  const int wm = w & 1, wn = w >> 1;
  const int sr = tid >> 1, sp = tid & 1;

  f32x4 acc[4][4];
  #pragma unroll
  for (int i = 0; i < 4; i++) {
    #pragma unroll
    for (int j = 0; j < 4; j++) acc[i][j] = (f32x4){0.f, 0.f, 0.f, 0.f};
  }

  const int m_ = M0 + sr;
  const int bb = m_ >> 9, tt = m_ & 511;       // m = b*512 + t
  const uint32_t* hbase = hh + ((size_t)(tt + 1) * 4 + (bb >> 4)) * (64 * 64)
                             + (size_t)(bb & 15) * 4;

  for (int K0 = 0; K0 < HH_; K0 += 32) {
    __syncthreads();
    {
      const int G0 = (K0 + sp * 16) >> 3;       // 8-unit group index
      const uint4 ch0 = *(const uint4*)(hbase + (size_t)G0 * 64);
      const uint4 ch1 = *(const uint4*)(hbase + (size_t)(G0 + 1) * 64);
      *(uint4*)&As[sr][sp * 16]     = ch0;
      *(uint4*)&As[sr][sp * 16 + 8] = ch1;
      const float* s1 = fcW + (size_t)(N0 + sr) * HH_ + K0 + sp * 16;
      float4 g0 = ((const float4*)s1)[0], g1 = ((const float4*)s1)[1];
      float4 g2 = ((const float4*)s1)[2], g3 = ((const float4*)s1)[3];
      *(half8*)&Bs[sr][sp * 16]     = cvt8(g0, g1);
      *(half8*)&Bs[sr][sp * 16 + 8] = cvt8(g2, g3);
    }
    __syncthreads();
    half8 af[4], bf[4];
    #pragma unroll
    for (int i = 0; i < 4; i++) af[i] = *(const half8*)&As[wm * 64 + i * 16 + ln][lg * 8];
    #pragma unroll
    for (int j = 0; j < 4; j++) bf[j] = *(const half8*)&Bs[wn * 64 + j * 16 + ln][lg * 8];
    #pragma unroll
    for (int i = 0; i < 4; i++) {
      #pragma unroll
      for (int j = 0; j < 4; j++)
        acc[i][j] = __builtin_amdgcn_mfma_f32_16x16x32_f16(af[i], bf[j], acc[i][j], 0, 0, 0);
    }
  }

  #pragma unroll
  for (int j = 0; j < 4; j++) {
    const int ncol = N0 + wn * 64 + j * 16 + ln;
    const float bias = fcb[ncol];
    #pragma unroll
    for (int i = 0; i < 4; i++) {
      #pragma unroll
      for (int rr = 0; rr < 4; rr++) {
        const int m = M0 + wm * 64 + i * 16 + lg * 4 + rr;
        out[(size_t)m * OO_ + ncol] = acc[i][j][rr] + bias;
      }
    }
  }
}

extern "C" void kernel_launch(void* const* d_in, const int* in_sizes, int n_in,
                              void* d_out, int out_size, void* d_ws, size_t ws_size,
                              hipStream_t stream) {
  (void)in_sizes; (void)n_in; (void)out_size;
  if (ws_size < WS_NEEDED) return;  // diagnostic: output stays zero -> absmax ~0.39

  const float* x   = (const float*)d_in[0];
  const float* Wih = (const float*)d_in[1];
  const float* Whh = (const float*)d_in[2];
  const float* bih = (const float*)d_in[3];
  const float* bhh = (const float*)d_in[4];
  const float* fcW = (const float*)d_in[5];
  const float* fcb = (const float*)d_in[6];
  float* out = (float*)d_out;

  char* ws = (char*)d_ws;
  _Float16* gx  = (_Float16*)(ws + GX_OFF);
  uint32_t* hh  = (uint32_t*)(ws + HH_OFF);
  int* flags    = (int*)(ws + FLAG_OFF);

  // reset slot 0 (= h_0 = 0) and flags every call (graph replays reuse ws)
  (void)hipMemsetAsync(ws + HH_OFF, 0, (size_t)4 * 64 * 256, stream);
  (void)hipMemsetAsync(ws + FLAG_OFF, 0, FLAG_BYTES, stream);

  gates_gemm_k<<<dim3(4096), dim3(256), 0, stream>>>(x, Wih, bih, bhh, gx);
  lstm_rec_k<<<dim3(64), dim3(256), 0, stream>>>(Whh, gx, hh, flags);
  fc_gemm_k<<<dim3(512), dim3(256), 0, stream>>>(hh, fcW, fcb, out);
}